// Round 4
// baseline (597.585 us; speedup 1.0000x reference)
//
#include <hip/hip_runtime.h>

// ---------------------------------------------------------------------------
// ExpandHarmonics: ragged expansion of reflections into Laue harmonics.
//   g      = gcd(h,k,l)
//   n_max  = floor(dHKL*g / dmin)
//   row i emits entries n = 1..n_max[i], compacted row-major.
// Outputs concatenated flat (promoted to float32):
//   [0,3M)     hkl_out   = (hkl/g)*n
//   [3M,4M)    dHKL_out  = (dHKL*g)/n
//   [4M,5M)    wl_out    = (wl*g)/n
//   [5M,37M)   meta_out  = meta[row]   (DMETA=32)
// M = out_size / 37 (harness-known total).
//
// R1: k_meta -> float4 (16B/lane) + NT stores.
// R2: clang ext_vector_type for NT 16B store.
// R4: fuse scalar outputs into k_expand (kills k_scalar's gathered loads +
//     pack re-read); k_count caches (nm<<8)|g per row in ws; shuffle-scan.
// ---------------------------------------------------------------------------

typedef float f32x4 __attribute__((ext_vector_type(4)));

__device__ __forceinline__ int gcd2(int a, int b) {
    while (b) { int t = a % b; a = b; b = t; }
    return a;
}
__device__ __forceinline__ int gcd3(int a, int b, int c) {
    return gcd2(gcd2(a, b), c);
}

// K1: per-row n_max & g -> rowinfo, per-block sum of n_max -> bsums
__global__ void k_count(const int* __restrict__ hkl, const float* __restrict__ dHKL,
                        const float* __restrict__ dmin_p,
                        int* __restrict__ rowinfo, int* __restrict__ bsums, int N) {
    int tid = threadIdx.x;
    int i = blockIdx.x * 256 + tid;
    int lane = tid & 63, wave = tid >> 6;
    int nm = 0;
    if (i < N) {
        int h = hkl[3 * i], k = hkl[3 * i + 1], l = hkl[3 * i + 2];
        int g = gcd3(h, k, l);
        float d0 = dHKL[i] * (float)g;              // same f32 op order as ref
        nm = (int)floorf(d0 / dmin_p[0]);           // jnp.floor_divide
        rowinfo[i] = (nm << 8) | g;                 // nm<=~150, g<=50: fits bytes
    }
    // wave reduce + 4-wave LDS combine
    int v = nm;
    #pragma unroll
    for (int off = 32; off > 0; off >>= 1) v += __shfl_down(v, off);
    __shared__ int ws4[4];
    if (lane == 0) ws4[wave] = v;
    __syncthreads();
    if (tid == 0) bsums[blockIdx.x] = ws4[0] + ws4[1] + ws4[2] + ws4[3];
}

// K2: exclusive scan of block sums (single block, wave-shuffle scan, 1024 thr)
__global__ void k_scan(const int* __restrict__ bsums, int* __restrict__ boffs, int nb) {
    __shared__ int wsums[16];
    __shared__ int carry_s;
    int tid = threadIdx.x, lane = tid & 63, wave = tid >> 6;
    if (tid == 0) carry_s = 0;
    __syncthreads();
    for (int t0 = 0; t0 < nb; t0 += 1024) {
        int idx = t0 + tid;
        int orig = (idx < nb) ? bsums[idx] : 0;
        int v = orig;
        #pragma unroll
        for (int off = 1; off < 64; off <<= 1) {
            int x = __shfl_up(v, off);
            if (lane >= off) v += x;
        }
        if (lane == 63) wsums[wave] = v;
        __syncthreads();
        int wbase = 0;
        #pragma unroll
        for (int w = 0; w < 16; w++) wbase += (w < wave) ? wsums[w] : 0;
        int carry = carry_s;
        __syncthreads();                              // all read carry before update
        if (idx < nb) boffs[idx] = carry + wbase + v - orig;   // exclusive
        if (tid == 1023) carry_s = carry + wbase + v;          // tile total
        __syncthreads();
    }
}

// K3: per-row base offset (block offset + intra-block shuffle scan);
//     write pack descriptor AND all per-entry scalar outputs.
__global__ void k_expand(const int* __restrict__ hkl, const float* __restrict__ dHKL,
                         const float* __restrict__ wl, const int* __restrict__ rowinfo,
                         const int* __restrict__ boffs, int* __restrict__ pack,
                         float* __restrict__ out, int N, int M) {
    int tid = threadIdx.x;
    int i = blockIdx.x * 256 + tid;
    int lane = tid & 63, wave = tid >> 6;
    int info = (i < N) ? rowinfo[i] : 0;
    int nm = info >> 8;
    int g  = info & 255;
    // intra-block exclusive scan of nm
    int v = nm;
    #pragma unroll
    for (int off = 1; off < 64; off <<= 1) {
        int x = __shfl_up(v, off);
        if (lane >= off) v += x;
    }
    __shared__ int ws4[4];
    if (lane == 63) ws4[wave] = v;
    __syncthreads();
    int wbase = 0;
    #pragma unroll
    for (int w = 0; w < 4; w++) wbase += (w < wave) ? ws4[w] : 0;
    int base = boffs[blockIdx.x] + wbase + v - nm;

    if (i < N && nm > 0) {
        int h = hkl[3 * i], k = hkl[3 * i + 1], l = hkl[3 * i + 2];
        int h0 = h / g, k0 = k / g, l0 = l / g;
        float dg = dHKL[i] * (float)g;                // d0, ref op order
        float wg = wl[i] * (float)g;                  // wavelength_0
        int p = (i << 8);
        for (int n = 1; n <= nm; n++) {
            int m = base + n - 1;
            if (m < M) {
                float nf = (float)n;
                pack[m] = p | n;
                __builtin_nontemporal_store((float)(h0 * n), &out[3 * m]);
                __builtin_nontemporal_store((float)(k0 * n), &out[3 * m + 1]);
                __builtin_nontemporal_store((float)(l0 * n), &out[3 * m + 2]);
                __builtin_nontemporal_store(dg / nf, &out[(size_t)3 * M + m]);
                __builtin_nontemporal_store(wg / nf, &out[(size_t)4 * M + m]);
            }
        }
    }
}

// K4: meta gather-scatter, one 16B vector per thread.
//   out5 = out + 5M (dword offset 5M may be misaligned for 16B; pad realigns).
//   Body thread t handles dwords p = pad + 4t .. +3 as one aligned 16B store.
//   Extra threads (t >= nbody4) handle the <4 head dwords and <4 tail dwords.
__global__ void k_meta4(const int* __restrict__ pack, const float* __restrict__ meta,
                        float* __restrict__ out5, int total, int pad,
                        int nbody4, int nextra, int N) {
    int t = blockIdx.x * 256 + threadIdx.x;
    if (t < nbody4) {
        int p = pad + (t << 2);
        int m0 = p >> 5;
        int ra = pack[m0] >> 8;
        if (ra >= N || ra < 0) ra = 0;                 // safety against poison
        f32x4 v;
        if (pad == 0) {
            // p % 4 == 0 and rows are 32 dwords: the 4 dwords never cross a row
            const f32x4* meta4 = (const f32x4*)meta;
            v = meta4[(ra << 3) + ((p & 31) >> 2)];
        } else {
            int m3 = (p + 3) >> 5;
            int rb = (m3 == m0) ? ra : (pack[m3] >> 8);
            if (rb >= N || rb < 0) rb = 0;
            {
                int pj = p;     int mj = pj >> 5; int rj = (mj == m0) ? ra : rb;
                v.x = meta[(rj << 5) + (pj & 31)];
            }
            {
                int pj = p + 1; int mj = pj >> 5; int rj = (mj == m0) ? ra : rb;
                v.y = meta[(rj << 5) + (pj & 31)];
            }
            {
                int pj = p + 2; int mj = pj >> 5; int rj = (mj == m0) ? ra : rb;
                v.z = meta[(rj << 5) + (pj & 31)];
            }
            {
                int pj = p + 3; int mj = pj >> 5; int rj = (mj == m0) ? ra : rb;
                v.w = meta[(rj << 5) + (pj & 31)];
            }
        }
        // (5M + p) % 4 == 0 by construction of pad -> 16B-aligned store
        __builtin_nontemporal_store(v, (f32x4*)(out5 + p));
    } else {
        int e = t - nbody4;
        if (e < nextra) {
            int p = (e < pad) ? e : (pad + (nbody4 << 2) + (e - pad));
            if (p < total) {
                int m = p >> 5;
                int r = pack[m] >> 8;
                if (r >= N || r < 0) r = 0;
                __builtin_nontemporal_store(meta[(r << 5) + (p & 31)], out5 + p);
            }
        }
    }
}

extern "C" void kernel_launch(void* const* d_in, const int* in_sizes, int n_in,
                              void* d_out, int out_size, void* d_ws, size_t ws_size,
                              hipStream_t stream) {
    const int*   hkl  = (const int*)d_in[0];
    const float* dHKL = (const float*)d_in[1];
    const float* wl   = (const float*)d_in[2];
    const float* meta = (const float*)d_in[3];
    const float* dmin = (const float*)d_in[4];
    float* out = (float*)d_out;

    int N = in_sizes[0] / 3;
    int M = out_size / 37;
    int nb = (N + 255) / 256;

    int* rowinfo = (int*)d_ws;        // [N]
    int* bsums   = rowinfo + N;       // [nb]
    int* boffs   = bsums + nb;        // [nb]
    int* pack    = boffs + nb;        // [M]

    k_count<<<nb, 256, 0, stream>>>(hkl, dHKL, dmin, rowinfo, bsums, N);
    k_scan<<<1, 1024, 0, stream>>>(bsums, boffs, nb);
    k_expand<<<nb, 256, 0, stream>>>(hkl, dHKL, wl, rowinfo, boffs, pack, out, N, M);

    // meta: 16B body + scalar head/tail, aligned via pad
    int total = 32 * M;                      // dwords of meta_out
    int base  = 5 * M;                       // dword offset of meta_out in out
    int pad   = (4 - (base & 3)) & 3;
    if (pad > total) pad = total;
    int body   = total - pad;
    int nbody4 = body >> 2;
    int tail   = body & 3;
    int nextra = pad + tail;
    int g5 = (nbody4 + nextra + 255) / 256;
    k_meta4<<<g5, 256, 0, stream>>>(pack, meta, out + (size_t)5 * M,
                                    total, pad, nbody4, nextra, N);
}